// Round 2
// baseline (56.930 us; speedup 1.0000x reference)
//
#include <hip/hip_runtime.h>
#include <hip/hip_bf16.h>

// Problem constants
constexpr int Bn = 4096;   // batch
constexpr int Vn = 64;     // nodes
constexpr int Hn = 512;    // hidden

typedef __attribute__((ext_vector_type(8))) short bf16x8;
typedef __attribute__((ext_vector_type(4))) float f32x4;
typedef __attribute__((ext_vector_type(8))) unsigned short u16x8;

__device__ __forceinline__ unsigned short f2bf(float f) {
    union { float f; unsigned int u; } x; x.f = f;
    unsigned int u = x.u;
    u += 0x7fffu + ((u >> 16) & 1u);   // round-to-nearest-even
    return (unsigned short)(u >> 16);
}

// ---------------------------------------------------------------------------
// Prep 1: W1w[v][k][n] = sigmoid(adjw[v][k]) * W1[v][k-(k>v)][n]  (0 if k==v)
// stored in mfma_f32_16x16x32_bf16 B-fragment layout:
//   flat = (((v*32 + nt)*2 + ks)*64 + lane)*8 + e
//   where n = nt*16 + (lane&15), k = ks*32 + (lane>>4)*8 + e
// ---------------------------------------------------------------------------
__global__ void prep_w1(const float* __restrict__ adjw,
                        const float* __restrict__ W1,
                        unsigned short* __restrict__ bfrag) {
    int tid  = blockIdx.x * blockDim.x + threadIdx.x;   // 262144 threads
    int lane = tid & 63;
    int ks   = (tid >> 6) & 1;
    int nt   = (tid >> 7) & 31;
    int v    = tid >> 12;

    int n     = nt * 16 + (lane & 15);
    int kbase = ks * 32 + ((lane >> 4) << 3);

    u16x8 o;
#pragma unroll
    for (int e = 0; e < 8; ++e) {
        int k = kbase + e;
        float val = 0.f;
        if (k != v) {
            float aw = adjw[v * Vn + k];
            float s  = 1.f / (1.f + __expf(-aw));
            int  j   = k - (k > v);
            val = s * W1[((size_t)(v * (Vn - 1) + j)) * Hn + n];
        }
        o[e] = f2bf(val);
    }
    *reinterpret_cast<u16x8*>(bfrag + (size_t)tid * 8) = o;
}

// ---------------------------------------------------------------------------
// Prep 2: x (B x V fp32) -> bf16 A-fragment layout:
//   flat = ((mt*2 + ks)*64 + lane)*8 + e
//   where b = mt*16 + (lane&15), k = ks*32 + (lane>>4)*8 + e
// ---------------------------------------------------------------------------
__global__ void prep_x(const float* __restrict__ x,
                       unsigned short* __restrict__ afrag) {
    int tid  = blockIdx.x * blockDim.x + threadIdx.x;   // 32768 threads
    int lane = tid & 63;
    int ks   = (tid >> 6) & 1;
    int mt   = tid >> 7;

    int b     = mt * 16 + (lane & 15);
    int kbase = ks * 32 + ((lane >> 4) << 3);

    u16x8 o;
#pragma unroll
    for (int e = 0; e < 8; ++e)
        o[e] = f2bf(x[(size_t)b * Vn + kbase + e]);
    *reinterpret_cast<u16x8*>(afrag + (size_t)tid * 8) = o;
}

// ---------------------------------------------------------------------------
// Main: block (btile, v) covers 64 rows of out[:, v]. 8 waves (512 thr);
// wave w owns n-tiles w*4..w*4+3. ALL operand loads issued upfront
// (straight-line, ~22 outstanding), b1 folded into MFMA C-init, epilogue is
// relu+fma only, then 16-lane shuffle reduce + LDS cross-wave reduce.
// ---------------------------------------------------------------------------
__global__ __launch_bounds__(512)
void main_k(const unsigned short* __restrict__ afrag,
            const unsigned short* __restrict__ bfrag,
            const float* __restrict__ b1, const float* __restrict__ W2,
            const float* __restrict__ b2, float* __restrict__ out) {
    int btile = blockIdx.x;          // 0..63 (64 rows each)
    int v     = blockIdx.y;          // 0..63
    int wid   = threadIdx.x >> 6;    // 0..7
    int lane  = threadIdx.x & 63;

    // A fragments: 4 m-tiles x 2 k-steps (identical across waves; L1-hot)
    bf16x8 a[4][2];
#pragma unroll
    for (int m = 0; m < 4; ++m)
#pragma unroll
        for (int ks = 0; ks < 2; ++ks) {
            int mt = btile * 4 + m;
            a[m][ks] = *reinterpret_cast<const bf16x8*>(
                afrag + ((size_t)(mt * 2 + ks)) * 512 + lane * 8);
        }

    // B fragments: this wave's 4 n-tiles x 2 k-steps, all upfront
    bf16x8 bfr[4][2];
#pragma unroll
    for (int j = 0; j < 4; ++j)
#pragma unroll
        for (int ks = 0; ks < 2; ++ks) {
            int nt = wid * 4 + j;
            bfr[j][ks] = *reinterpret_cast<const bf16x8*>(
                bfrag + ((size_t)((v * 32 + nt) * 2 + ks)) * 512 + lane * 8);
        }

    // Per-n-tile scalars (col n = nt*16 + (lane&15))
    float w2v[4], b1v[4];
#pragma unroll
    for (int j = 0; j < 4; ++j) {
        int n = (wid * 4 + j) * 16 + (lane & 15);
        w2v[j] = W2[v * Hn + n];
        b1v[j] = b1[v * Hn + n];
    }

    float partial[4][4] = {};

#pragma unroll
    for (int j = 0; j < 4; ++j) {
#pragma unroll
        for (int m = 0; m < 4; ++m) {
            f32x4 c = {b1v[j], b1v[j], b1v[j], b1v[j]};
            c = __builtin_amdgcn_mfma_f32_16x16x32_bf16(a[m][0], bfr[j][0], c, 0, 0, 0);
            c = __builtin_amdgcn_mfma_f32_16x16x32_bf16(a[m][1], bfr[j][1], c, 0, 0, 0);
#pragma unroll
            for (int r = 0; r < 4; ++r)
                partial[m][r] = fmaf(fmaxf(c[r], 0.f), w2v[j], partial[m][r]);
        }
    }

    // reduce over the 16-lane column group (bits 0..3 of lane)
#pragma unroll
    for (int m = 0; m < 4; ++m)
#pragma unroll
        for (int r = 0; r < 4; ++r) {
            float s = partial[m][r];
            s += __shfl_xor(s, 1);
            s += __shfl_xor(s, 2);
            s += __shfl_xor(s, 4);
            s += __shfl_xor(s, 8);
            partial[m][r] = s;
        }

    __shared__ float sdata[8][64];
    if ((lane & 15) == 0) {
        int hi = lane >> 4;
#pragma unroll
        for (int m = 0; m < 4; ++m)
#pragma unroll
            for (int r = 0; r < 4; ++r)
                sdata[wid][m * 16 + hi * 4 + r] = partial[m][r];
    }
    __syncthreads();

    if (threadIdx.x < 64) {
        int row = threadIdx.x;
        float s = b2[v];
#pragma unroll
        for (int w = 0; w < 8; ++w) s += sdata[w][row];
        out[(size_t)(btile * 64 + row) * Vn + v] = s;
    }
}

extern "C" void kernel_launch(void* const* d_in, const int* in_sizes, int n_in,
                              void* d_out, int out_size, void* d_ws, size_t ws_size,
                              hipStream_t stream) {
    const float* x    = (const float*)d_in[0];
    const float* adjw = (const float*)d_in[1];
    const float* W1   = (const float*)d_in[2];
    const float* b1   = (const float*)d_in[3];
    const float* W2   = (const float*)d_in[4];
    const float* b2   = (const float*)d_in[5];
    float* out = (float*)d_out;

    // workspace: bfrag = 64*64*512 u16 (4 MiB), afrag = 4096*64 u16 (512 KiB)
    unsigned short* bfrag = (unsigned short*)d_ws;
    unsigned short* afrag = bfrag + (size_t)Vn * Vn * Hn;

    prep_w1<<<262144 / 256, 256, 0, stream>>>(adjw, W1, bfrag);
    prep_x<<<32768 / 256, 256, 0, stream>>>(x, afrag);
    main_k<<<dim3(64, 64), 512, 0, stream>>>(afrag, bfrag, b1, W2, b2, out);
}

// Round 3
// 38.582 us; speedup vs baseline: 1.4756x; 1.4756x over previous
//
#include <hip/hip_runtime.h>
#include <hip/hip_bf16.h>

// Problem constants
constexpr int Bn = 4096;   // batch
constexpr int Vn = 64;     // nodes
constexpr int Hn = 512;    // hidden

typedef __attribute__((ext_vector_type(8))) short bf16x8;
typedef __attribute__((ext_vector_type(4))) float f32x4;
typedef __attribute__((ext_vector_type(8))) unsigned short u16x8;

__device__ __forceinline__ unsigned short f2bf(float f) {
    union { float f; unsigned int u; } x; x.f = f;
    unsigned int u = x.u;
    u += 0x7fffu + ((u >> 16) & 1u);   // round-to-nearest-even
    return (unsigned short)(u >> 16);
}

// ---------------------------------------------------------------------------
// Prep 1: W1w[v][k][n] = sigmoid(adjw[v][k]) * W1[v][k-(k>v)][n]  (0 if k==v)
// stored in mfma_f32_16x16x32_bf16 B-fragment layout:
//   flat = (((v*32 + nt)*2 + ks)*64 + lane)*8 + e
//   where n = nt*16 + (lane&15), k = ks*32 + (lane>>4)*8 + e
// ---------------------------------------------------------------------------
__global__ void prep_w1(const float* __restrict__ adjw,
                        const float* __restrict__ W1,
                        unsigned short* __restrict__ bfrag) {
    int tid  = blockIdx.x * blockDim.x + threadIdx.x;   // 262144 threads
    int lane = tid & 63;
    int ks   = (tid >> 6) & 1;
    int nt   = (tid >> 7) & 31;
    int v    = tid >> 12;

    int n     = nt * 16 + (lane & 15);
    int kbase = ks * 32 + ((lane >> 4) << 3);

    u16x8 o;
#pragma unroll
    for (int e = 0; e < 8; ++e) {
        int k = kbase + e;
        float val = 0.f;
        if (k != v) {
            float aw = adjw[v * Vn + k];
            float s  = 1.f / (1.f + __expf(-aw));
            int  j   = k - (k > v);
            val = s * W1[((size_t)(v * (Vn - 1) + j)) * Hn + n];
        }
        o[e] = f2bf(val);
    }
    *reinterpret_cast<u16x8*>(bfrag + (size_t)tid * 8) = o;
}

// ---------------------------------------------------------------------------
// Prep 2: x (B x V fp32) -> bf16 A-fragment layout:
//   flat = ((mt*2 + ks)*64 + lane)*8 + e
//   where b = mt*16 + (lane&15), k = ks*32 + (lane>>4)*8 + e
// ---------------------------------------------------------------------------
__global__ void prep_x(const float* __restrict__ x,
                       unsigned short* __restrict__ afrag) {
    int tid  = blockIdx.x * blockDim.x + threadIdx.x;   // 32768 threads
    int lane = tid & 63;
    int ks   = (tid >> 6) & 1;
    int mt   = tid >> 7;

    int b     = mt * 16 + (lane & 15);
    int kbase = ks * 32 + ((lane >> 4) << 3);

    u16x8 o;
#pragma unroll
    for (int e = 0; e < 8; ++e)
        o[e] = f2bf(x[(size_t)b * Vn + kbase + e]);
    *reinterpret_cast<u16x8*>(afrag + (size_t)tid * 8) = o;
}

// ---------------------------------------------------------------------------
// Main: one WAVE = one job (row-group rg of 64 batch rows x one v).
// No LDS, no barriers, waves fully independent. A (64x64) in regs; stream
// all 32 n-tiles of B with a 1-ahead double-buffered prefetch (static
// indices via full unroll). h-reduction completes in-wave (16-lane
// butterfly). 4096 jobs = 1024 blocks x 4 waves; 16 waves/CU.
// ---------------------------------------------------------------------------
__global__ __launch_bounds__(256, 4)
void main_k(const unsigned short* __restrict__ afrag,
            const unsigned short* __restrict__ bfrag,
            const float* __restrict__ b1, const float* __restrict__ W2,
            const float* __restrict__ b2, float* __restrict__ out) {
    int wid  = threadIdx.x >> 6;
    int lane = threadIdx.x & 63;
    int job  = blockIdx.x * 4 + wid;     // 0..4095, v-major
    int v    = job >> 6;
    int rg   = job & 63;                 // 64-row group

    // A fragments: 4 m-tiles x 2 k-steps (shared across the 64 jobs of a v;
    // L1/L2-hot)
    bf16x8 a[4][2];
#pragma unroll
    for (int m = 0; m < 4; ++m)
#pragma unroll
        for (int ks = 0; ks < 2; ++ks)
            a[m][ks] = *reinterpret_cast<const bf16x8*>(
                afrag + ((size_t)((rg * 4 + m) * 2 + ks)) * 512 + lane * 8);

    const unsigned short* bpan = bfrag + (size_t)v * 32 * 2 * 512;  // v's panel
    const float* w2row = W2 + v * Hn;
    const float* b1row = b1 + v * Hn;
    int ncol = lane & 15;

    // software-pipelined B stream: double-buffered, static indices
    bf16x8 pb0[2], pb1[2];
    float  pw2[2], pbv[2];
    pb0[0] = *reinterpret_cast<const bf16x8*>(bpan + 0 * 1024 + 0 + lane * 8);
    pb1[0] = *reinterpret_cast<const bf16x8*>(bpan + 0 * 1024 + 512 + lane * 8);
    pw2[0] = w2row[0 * 16 + ncol];
    pbv[0] = b1row[0 * 16 + ncol];

    float partial[4][4] = {};

#pragma unroll
    for (int j = 0; j < 32; ++j) {
        const int cur = j & 1, nxt = cur ^ 1;
        if (j < 31) {
            pb0[nxt] = *reinterpret_cast<const bf16x8*>(
                bpan + (size_t)(j + 1) * 1024 + 0 + lane * 8);
            pb1[nxt] = *reinterpret_cast<const bf16x8*>(
                bpan + (size_t)(j + 1) * 1024 + 512 + lane * 8);
            pw2[nxt] = w2row[(j + 1) * 16 + ncol];
            pbv[nxt] = b1row[(j + 1) * 16 + ncol];
        }
#pragma unroll
        for (int m = 0; m < 4; ++m) {
            f32x4 c = {pbv[cur], pbv[cur], pbv[cur], pbv[cur]};
            c = __builtin_amdgcn_mfma_f32_16x16x32_bf16(a[m][0], pb0[cur], c, 0, 0, 0);
            c = __builtin_amdgcn_mfma_f32_16x16x32_bf16(a[m][1], pb1[cur], c, 0, 0, 0);
#pragma unroll
            for (int r = 0; r < 4; ++r)
                partial[m][r] = fmaf(fmaxf(c[r], 0.f), pw2[cur], partial[m][r]);
        }
    }

    // reduce over the 16-lane column group (bits 0..3 of lane)
#pragma unroll
    for (int m = 0; m < 4; ++m)
#pragma unroll
        for (int r = 0; r < 4; ++r) {
            float s = partial[m][r];
            s += __shfl_xor(s, 1);
            s += __shfl_xor(s, 2);
            s += __shfl_xor(s, 4);
            s += __shfl_xor(s, 8);
            partial[m][r] = s;
        }

    float b2v = b2[v];
    if ((lane & 15) == 0) {
        int hi = lane >> 4;
#pragma unroll
        for (int m = 0; m < 4; ++m)
#pragma unroll
            for (int r = 0; r < 4; ++r) {
                int row = rg * 64 + m * 16 + hi * 4 + r;
                out[(size_t)row * Vn + v] = partial[m][r] + b2v;
            }
    }
}

extern "C" void kernel_launch(void* const* d_in, const int* in_sizes, int n_in,
                              void* d_out, int out_size, void* d_ws, size_t ws_size,
                              hipStream_t stream) {
    const float* x    = (const float*)d_in[0];
    const float* adjw = (const float*)d_in[1];
    const float* W1   = (const float*)d_in[2];
    const float* b1   = (const float*)d_in[3];
    const float* W2   = (const float*)d_in[4];
    const float* b2   = (const float*)d_in[5];
    float* out = (float*)d_out;

    // workspace: bfrag = 64*64*512 u16 (4 MiB), afrag = 4096*64 u16 (512 KiB)
    unsigned short* bfrag = (unsigned short*)d_ws;
    unsigned short* afrag = bfrag + (size_t)Vn * Vn * Hn;

    prep_w1<<<262144 / 256, 256, 0, stream>>>(adjw, W1, bfrag);
    prep_x<<<32768 / 256, 256, 0, stream>>>(x, afrag);
    main_k<<<1024, 256, 0, stream>>>(afrag, bfrag, b1, W2, b2, out);
}

// Round 4
// 33.331 us; speedup vs baseline: 1.7080x; 1.1575x over previous
//
#include <hip/hip_runtime.h>
#include <hip/hip_bf16.h>

// Problem constants
constexpr int Bn = 4096;   // batch
constexpr int Vn = 64;     // nodes
constexpr int Hn = 512;    // hidden

typedef __attribute__((ext_vector_type(8))) short bf16x8;
typedef __attribute__((ext_vector_type(4))) float f32x4;
typedef __attribute__((ext_vector_type(8))) unsigned short u16x8;

__device__ __forceinline__ unsigned short f2bf(float f) {
    union { float f; unsigned int u; } x; x.f = f;
    unsigned int u = x.u;
    u += 0x7fffu + ((u >> 16) & 1u);   // round-to-nearest-even
    return (unsigned short)(u >> 16);
}

// ---------------------------------------------------------------------------
// Prep 1: W1w[v][k][n] = sigmoid(adjw[v][k]) * W1[v][k-(k>v)][n]  (0 if k==v)
// stored in mfma_f32_16x16x32_bf16 B-fragment layout:
//   flat = (((v*32 + nt)*2 + ks)*64 + lane)*8 + e
//   where n = nt*16 + (lane&15), k = ks*32 + (lane>>4)*8 + e
// ---------------------------------------------------------------------------
__global__ void prep_w1(const float* __restrict__ adjw,
                        const float* __restrict__ W1,
                        unsigned short* __restrict__ bfrag) {
    int tid  = blockIdx.x * blockDim.x + threadIdx.x;   // 262144 threads
    int lane = tid & 63;
    int ks   = (tid >> 6) & 1;
    int nt   = (tid >> 7) & 31;
    int v    = tid >> 12;

    int n     = nt * 16 + (lane & 15);
    int kbase = ks * 32 + ((lane >> 4) << 3);

    u16x8 o;
#pragma unroll
    for (int e = 0; e < 8; ++e) {
        int k = kbase + e;
        float val = 0.f;
        if (k != v) {
            float aw = adjw[v * Vn + k];
            float s  = 1.f / (1.f + __expf(-aw));
            int  j   = k - (k > v);
            val = s * W1[((size_t)(v * (Vn - 1) + j)) * Hn + n];
        }
        o[e] = f2bf(val);
    }
    *reinterpret_cast<u16x8*>(bfrag + (size_t)tid * 8) = o;
}

// ---------------------------------------------------------------------------
// Prep 2: x (B x V fp32) -> bf16 A-fragment layout:
//   flat = ((mt*2 + ks)*64 + lane)*8 + e
//   where b = mt*16 + (lane&15), k = ks*32 + (lane>>4)*8 + e
// ---------------------------------------------------------------------------
__global__ void prep_x(const float* __restrict__ x,
                       unsigned short* __restrict__ afrag) {
    int tid  = blockIdx.x * blockDim.x + threadIdx.x;   // 32768 threads
    int lane = tid & 63;
    int ks   = (tid >> 6) & 1;
    int mt   = tid >> 7;

    int b     = mt * 16 + (lane & 15);
    int kbase = ks * 32 + ((lane >> 4) << 3);

    u16x8 o;
#pragma unroll
    for (int e = 0; e < 8; ++e)
        o[e] = f2bf(x[(size_t)b * Vn + kbase + e]);
    *reinterpret_cast<u16x8*>(afrag + (size_t)tid * 8) = o;
}

// ---------------------------------------------------------------------------
// Main: one WAVE = one job (64 batch rows x one v). No LDS/barriers.
// XCD-bijective block swizzle: XCD x serves only v in [x*8, x*8+8) so each
// XCD's L2 holds just 8 B-panels (512 KiB) + afrag (512 KiB) -> L2-hit
// latency on all B loads. 2-deep B prefetch (3 static buffers, full unroll)
// hides the ~200cyc L2 hit under 4 waves/SIMD.
// ---------------------------------------------------------------------------
__global__ __launch_bounds__(256, 4)
void main_k(const unsigned short* __restrict__ afrag,
            const unsigned short* __restrict__ bfrag,
            const float* __restrict__ b1, const float* __restrict__ W2,
            const float* __restrict__ b2, float* __restrict__ out) {
    int wid  = threadIdx.x >> 6;
    int lane = threadIdx.x & 63;
    // bijective XCD swizzle: 1024 blocks = 8 XCDs x 128
    int nb   = (blockIdx.x & 7) * 128 + (blockIdx.x >> 3);
    int job  = nb * 4 + wid;             // 0..4095, v-major
    int v    = job >> 6;
    int rg   = job & 63;                 // 64-row group

    // A fragments: 4 m-tiles x 2 k-steps
    bf16x8 a[4][2];
#pragma unroll
    for (int m = 0; m < 4; ++m)
#pragma unroll
        for (int ks = 0; ks < 2; ++ks)
            a[m][ks] = *reinterpret_cast<const bf16x8*>(
                afrag + ((size_t)((rg * 4 + m) * 2 + ks)) * 512 + lane * 8);

    const unsigned short* bpan = bfrag + (size_t)v * 32 * 2 * 512;  // v's panel
    const float* w2row = W2 + v * Hn;
    const float* b1row = b1 + v * Hn;
    int ncol = lane & 15;

    // 2-deep software pipeline: 3 static B buffers (indices compile-time
    // constant under full unroll)
    bf16x8 pb0[3], pb1[3];
    float  pw2[3], pbv[3];
#pragma unroll
    for (int p = 0; p < 2; ++p) {
        pb0[p] = *reinterpret_cast<const bf16x8*>(bpan + (size_t)p * 1024 + 0 + lane * 8);
        pb1[p] = *reinterpret_cast<const bf16x8*>(bpan + (size_t)p * 1024 + 512 + lane * 8);
        pw2[p] = w2row[p * 16 + ncol];
        pbv[p] = b1row[p * 16 + ncol];
    }

    float partial[4][4] = {};

#pragma unroll
    for (int j = 0; j < 32; ++j) {
        const int cur = j % 3;
        if (j < 30) {
            const int nxt = (j + 2) % 3;
            pb0[nxt] = *reinterpret_cast<const bf16x8*>(
                bpan + (size_t)(j + 2) * 1024 + 0 + lane * 8);
            pb1[nxt] = *reinterpret_cast<const bf16x8*>(
                bpan + (size_t)(j + 2) * 1024 + 512 + lane * 8);
            pw2[nxt] = w2row[(j + 2) * 16 + ncol];
            pbv[nxt] = b1row[(j + 2) * 16 + ncol];
        }
#pragma unroll
        for (int m = 0; m < 4; ++m) {
            f32x4 c = {pbv[cur], pbv[cur], pbv[cur], pbv[cur]};
            c = __builtin_amdgcn_mfma_f32_16x16x32_bf16(a[m][0], pb0[cur], c, 0, 0, 0);
            c = __builtin_amdgcn_mfma_f32_16x16x32_bf16(a[m][1], pb1[cur], c, 0, 0, 0);
#pragma unroll
            for (int r = 0; r < 4; ++r)
                partial[m][r] = fmaf(fmaxf(c[r], 0.f), pw2[cur], partial[m][r]);
        }
    }

    // reduce over the 16-lane column group (bits 0..3 of lane)
#pragma unroll
    for (int m = 0; m < 4; ++m)
#pragma unroll
        for (int r = 0; r < 4; ++r) {
            float s = partial[m][r];
            s += __shfl_xor(s, 1);
            s += __shfl_xor(s, 2);
            s += __shfl_xor(s, 4);
            s += __shfl_xor(s, 8);
            partial[m][r] = s;
        }

    float b2v = b2[v];
    if ((lane & 15) == 0) {
        int hi = lane >> 4;
#pragma unroll
        for (int m = 0; m < 4; ++m)
#pragma unroll
            for (int r = 0; r < 4; ++r) {
                int row = rg * 64 + m * 16 + hi * 4 + r;
                out[(size_t)row * Vn + v] = partial[m][r] + b2v;
            }
    }
}

extern "C" void kernel_launch(void* const* d_in, const int* in_sizes, int n_in,
                              void* d_out, int out_size, void* d_ws, size_t ws_size,
                              hipStream_t stream) {
    const float* x    = (const float*)d_in[0];
    const float* adjw = (const float*)d_in[1];
    const float* W1   = (const float*)d_in[2];
    const float* b1   = (const float*)d_in[3];
    const float* W2   = (const float*)d_in[4];
    const float* b2   = (const float*)d_in[5];
    float* out = (float*)d_out;

    // workspace: bfrag = 64*64*512 u16 (4 MiB), afrag = 4096*64 u16 (512 KiB)
    unsigned short* bfrag = (unsigned short*)d_ws;
    unsigned short* afrag = bfrag + (size_t)Vn * Vn * Hn;

    prep_w1<<<262144 / 256, 256, 0, stream>>>(adjw, W1, bfrag);
    prep_x<<<32768 / 256, 256, 0, stream>>>(x, afrag);
    main_k<<<1024, 256, 0, stream>>>(afrag, bfrag, b1, W2, b2, out);
}